// Round 11
// baseline (178.938 us; speedup 1.0000x reference)
//
#include <hip/hip_runtime.h>

// Problem constants (B=8, Tq=Tv=512, D=512, U=128)
constexpr int Bb = 8;
constexpr int Tq = 512;
constexpr int Tv = 512;
constexpr int Dd = 512;
constexpr int Uu = 128;
constexpr float C2LOG2E = 2.88539008177792681f;   // 2*log2(e)
constexpr float LOG2E   = 1.44269504088896341f;

// ---------------------------------------------------------------------------
// Kernel A: projections. 16 rows/block, 256 threads, 512 blocks.
// q half -> qf2[row][u] row-major. k half -> compact kT[b][u][pos[j]]; the
// 16 pos values are computed in-block by a 64-lane ballot scan of the mask
// (masked rows skipped). Both premultiplied by 2*log2e.
// ---------------------------------------------------------------------------
__global__ __launch_bounds__(256) void proj_kernel(
    const float* __restrict__ query,
    const float* __restrict__ key,
    const float* __restrict__ Wa,
    const float* __restrict__ Ua,
    const int* __restrict__ mask,
    float* __restrict__ qf2, float* __restrict__ kT)
{
    const int R    = blockIdx.x * 16;              // 0..8191
    const bool isQ = R < Bb * Tq;
    const float* __restrict__ src = isQ ? query : key;
    const float* __restrict__ W   = isQ ? Wa : Ua;
    const int Rloc = isQ ? R : R - Bb * Tq;        // 0..4095

    __shared__ float x[16 * Dd];                   // 32 KB
    __shared__ int posLoc[16];
    const int t = threadIdx.x;

    {   // stage 16 rows: 2048 float4, coalesced
        const float4* __restrict__ s4 =
            reinterpret_cast<const float4*>(src + (size_t)Rloc * Dd);
        float4* x4 = reinterpret_cast<float4*>(x);
#pragma unroll
        for (int m = 0; m < 8; ++m) x4[t + 256 * m] = s4[t + 256 * m];
    }
    if (!isQ && t < 64) {                          // wave-0 ballot scan -> pos
        const int b  = Rloc >> 9;
        const int j0 = Rloc & 511;                 // 16-aligned
        int base = 0;
#pragma unroll
        for (int c = 0; c < 8; ++c) {
            const int j = c * 64 + t;
            const int v = (mask[b * 512 + j] != 0);
            const unsigned long long bits = __ballot(v);
            const int pos = base + (int)__popcll(bits & ((1ull << t) - 1ull));
            if (j >= j0 && j < j0 + 16) posLoc[j - j0] = v ? pos : -1;
            base += (int)__popcll(bits);
        }
    }
    __syncthreads();

    const int ub = t & 63;
    const int rh = t >> 6;                         // 0..3
    float acc[4][2] = {{0,0},{0,0},{0,0},{0,0}};

#pragma unroll 2
    for (int d4 = 0; d4 < Dd / 4; ++d4) {
        const int d = d4 * 4;
        const float w0x = W[(d + 0) * Uu + ub],      w1x = W[(d + 0) * Uu + ub + 64];
        const float w0y = W[(d + 1) * Uu + ub],      w1y = W[(d + 1) * Uu + ub + 64];
        const float w0z = W[(d + 2) * Uu + ub],      w1z = W[(d + 2) * Uu + ub + 64];
        const float w0w = W[(d + 3) * Uu + ub],      w1w = W[(d + 3) * Uu + ub + 64];
#pragma unroll
        for (int k = 0; k < 4; ++k) {
            const float4 xv = *reinterpret_cast<const float4*>(x + (rh * 4 + k) * Dd + d);
            acc[k][0] = fmaf(xv.x, w0x, acc[k][0]);
            acc[k][0] = fmaf(xv.y, w0y, acc[k][0]);
            acc[k][0] = fmaf(xv.z, w0z, acc[k][0]);
            acc[k][0] = fmaf(xv.w, w0w, acc[k][0]);
            acc[k][1] = fmaf(xv.x, w1x, acc[k][1]);
            acc[k][1] = fmaf(xv.y, w1y, acc[k][1]);
            acc[k][1] = fmaf(xv.z, w1z, acc[k][1]);
            acc[k][1] = fmaf(xv.w, w1w, acc[k][1]);
        }
    }

    if (isQ) {
#pragma unroll
        for (int k = 0; k < 4; ++k) {
            const size_t row = (size_t)(Rloc + rh * 4 + k);
            qf2[row * Uu + ub]      = C2LOG2E * acc[k][0];
            qf2[row * Uu + ub + 64] = C2LOG2E * acc[k][1];
        }
    } else {
        float* __restrict__ kb = kT + (size_t)(Rloc >> 9) * Uu * Tv;
#pragma unroll
        for (int k = 0; k < 4; ++k) {
            const int p = posLoc[rh * 4 + k];
            if (p >= 0) {
                kb[(size_t)ub        * Tv + p] = C2LOG2E * acc[k][0];
                kb[(size_t)(ub + 64) * Tv + p] = C2LOG2E * acc[k][1];
            }
        }
    }
}

// ---------------------------------------------------------------------------
// Kernel B: attention over COMPACT keys. 8 query rows/block, 512 threads,
// 512 blocks. jl/cnt built in-block by ballot scan.
//   score : thread (s=t&255, uh=t>>8): jc = s (+256), u4 range uh*16..+16;
//           uh=1 partials -> pbuf, uh=0 combines -> w. Uniform barrier count.
//   softmax: wave wv -> row wv, over [0,cnt).
//   context: group g (0/1) owns a 4-aligned compact j-range; value rows via
//            jl indirection; partials combined via LDS (pbuf reused).
// ---------------------------------------------------------------------------
__global__ __launch_bounds__(512) void attn_kernel(
    const float* __restrict__ qf2, const float* __restrict__ kT,
    const float* __restrict__ value,
    const int* __restrict__ mask,
    const float* __restrict__ scale,
    float* __restrict__ out)
{
    const int r0 = blockIdx.x * 8;            // first query row (0..4095)
    const int b  = r0 >> 9;
    const int t  = threadIdx.x;               // 0..511

    __shared__ float q2[8 * Uu];              // 4 KB
    __shared__ float s2[Uu];                  // 0.5 KB
    __shared__ int   jl[Tv];                  // 2 KB
    __shared__ float w[8 * Tv];               // 16 KB
    __shared__ float pbuf[8 * Tv];            // 16 KB (score partials, then context)
    __shared__ float inv8[8];
    __shared__ int   cntS;

    jl[t] = 0;
    if (t < 256)
        reinterpret_cast<float4*>(q2)[t] =
            reinterpret_cast<const float4*>(qf2 + (size_t)r0 * Uu)[t];
    else if (t < 384) s2[t - 256] = scale[t - 256];
    __syncthreads();
    if (t < 64) {                             // wave-0 ballot scan -> jl, cnt
        int base = 0;
#pragma unroll
        for (int c = 0; c < 8; ++c) {
            const int j = c * 64 + t;
            const int v = (mask[b * 512 + j] != 0);
            const unsigned long long bits = __ballot(v);
            const int pos = base + (int)__popcll(bits & ((1ull << t) - 1ull));
            if (v) jl[pos] = j;
            base += (int)__popcll(bits);
        }
        if (t == 0) cntS = base;
    }
    __syncthreads();

    const int cnt   = cntS;
    const int cntp4 = (cnt + 3) & ~3;

    // ---- scores: u-split across thread halves ----
    const int s  = t & 255;
    const int uh = t >> 8;                    // 0/1
    const int u4b = uh * 16;                  // u4 in [u4b, u4b+16)
    const int niter = (cntp4 + 255) >> 8;     // 1 or 2, block-uniform
    for (int it = 0; it < niter; ++it) {
        const int jc = s + it * 256;
        float acc[8] = {0,0,0,0,0,0,0,0};
        if (jc < cnt) {
            const float* __restrict__ kb = kT + (size_t)b * Uu * Tv + jc;
#pragma unroll 2
            for (int u4 = u4b; u4 < u4b + 16; ++u4) {
                const float kx = kb[(size_t)(u4 * 4 + 0) * Tv];
                const float ky = kb[(size_t)(u4 * 4 + 1) * Tv];
                const float kz = kb[(size_t)(u4 * 4 + 2) * Tv];
                const float kw = kb[(size_t)(u4 * 4 + 3) * Tv];
                const float4 sv = reinterpret_cast<const float4*>(s2)[u4];
#pragma unroll
                for (int i = 0; i < 8; ++i) {
                    const float4 qv = *reinterpret_cast<const float4*>(q2 + i * Uu + u4 * 4);
                    float e0 = __builtin_amdgcn_exp2f(qv.x + kx);
                    float e1 = __builtin_amdgcn_exp2f(qv.y + ky);
                    float e2 = __builtin_amdgcn_exp2f(qv.z + kz);
                    float e3 = __builtin_amdgcn_exp2f(qv.w + kw);
                    acc[i] = fmaf(sv.x, __builtin_amdgcn_rcpf(e0 + 1.f), acc[i]);
                    acc[i] = fmaf(sv.y, __builtin_amdgcn_rcpf(e1 + 1.f), acc[i]);
                    acc[i] = fmaf(sv.z, __builtin_amdgcn_rcpf(e2 + 1.f), acc[i]);
                    acc[i] = fmaf(sv.w, __builtin_amdgcn_rcpf(e3 + 1.f), acc[i]);
                }
            }
        }
        if (uh == 1 && jc < cnt) {
#pragma unroll
            for (int i = 0; i < 8; ++i) pbuf[i * Tv + jc] = acc[i];
        }
        __syncthreads();
        if (uh == 0 && jc < cntp4) {
            if (jc < cnt) {
#pragma unroll
                for (int i = 0; i < 8; ++i)
                    w[i * Tv + jc] = -2.f * (acc[i] + pbuf[i * Tv + jc]);
            } else {
#pragma unroll
                for (int i = 0; i < 8; ++i) w[i * Tv + jc] = 0.f;
            }
        }
        __syncthreads();
    }

    // ---- softmax over [0,cnt): wave wv handles row wv ----
    {
        const int wv = t >> 6, ln = t & 63;
        float* __restrict__ row = w + wv * Tv;
        float vals[8];
        float m = -3e38f;
#pragma unroll
        for (int c = 0; c < 8; ++c) {
            const int e = ln + 64 * c;
            vals[c] = (e < cnt) ? row[e] : -3e38f;
            m = fmaxf(m, vals[c]);
        }
#pragma unroll
        for (int off = 32; off; off >>= 1) m = fmaxf(m, __shfl_xor(m, off, 64));
        float sum = 0.f;
#pragma unroll
        for (int c = 0; c < 8; ++c) {
            const int e = ln + 64 * c;
            if (e < cnt) {
                float ex = __builtin_amdgcn_exp2f((vals[c] - m) * LOG2E);
                row[e] = ex;
                sum += ex;
            }
        }
#pragma unroll
        for (int off = 32; off; off >>= 1) sum += __shfl_xor(sum, off, 64);
        if (ln == 0) inv8[wv] = 1.0f / sum;
    }
    __syncthreads();

    // ---- context over compact rows: group g owns a 4-aligned range ----
    const int mid  = ((cntp4 >> 1) + 3) & ~3;
    const int g  = t >> 8;                 // 0/1
    const int c  = t & 255;
    const int d0 = c * 2;
    const int jbeg = g ? mid : 0;
    const int jend = g ? cntp4 : mid;
    const float* __restrict__ vb = value + (size_t)b * Tv * Dd + d0;
    float ax[8], ay[8];
#pragma unroll
    for (int i = 0; i < 8; ++i) { ax[i] = 0.f; ay[i] = 0.f; }

    for (int jj = jbeg; jj < jend; jj += 4) {
        const int4 rows = *reinterpret_cast<const int4*>(jl + jj);
        const float2 v0 = *reinterpret_cast<const float2*>(vb + (size_t)rows.x * Dd);
        const float2 v1 = *reinterpret_cast<const float2*>(vb + (size_t)rows.y * Dd);
        const float2 v2 = *reinterpret_cast<const float2*>(vb + (size_t)rows.z * Dd);
        const float2 v3 = *reinterpret_cast<const float2*>(vb + (size_t)rows.w * Dd);
#pragma unroll
        for (int i = 0; i < 8; ++i) {
            const float4 wq = *reinterpret_cast<const float4*>(w + i * Tv + jj); // broadcast
            ax[i] = fmaf(wq.x, v0.x, ax[i]); ay[i] = fmaf(wq.x, v0.y, ay[i]);
            ax[i] = fmaf(wq.y, v1.x, ax[i]); ay[i] = fmaf(wq.y, v1.y, ay[i]);
            ax[i] = fmaf(wq.z, v2.x, ax[i]); ay[i] = fmaf(wq.z, v2.y, ay[i]);
            ax[i] = fmaf(wq.w, v3.x, ax[i]); ay[i] = fmaf(wq.w, v3.y, ay[i]);
        }
    }

    __syncthreads();                       // pbuf free for reuse
    if (g == 1) {
#pragma unroll
        for (int i = 0; i < 8; ++i) {
            float2 p; p.x = ax[i]; p.y = ay[i];
            *reinterpret_cast<float2*>(pbuf + i * Tv + d0) = p;
        }
    }
    __syncthreads();
    if (g == 0) {
#pragma unroll
        for (int i = 0; i < 8; ++i) {
            const float inv = inv8[i];
            const float2 p1 = *reinterpret_cast<const float2*>(pbuf + i * Tv + d0);
            float2 o;
            o.x = (ax[i] + p1.x) * inv;
            o.y = (ay[i] + p1.y) * inv;
            *reinterpret_cast<float2*>(out + (size_t)(r0 + i) * Dd + d0) = o;
        }
    }
}

extern "C" void kernel_launch(void* const* d_in, const int* in_sizes, int n_in,
                              void* d_out, int out_size, void* d_ws, size_t ws_size,
                              hipStream_t stream)
{
    const float* query = (const float*)d_in[0];
    const float* key   = (const float*)d_in[1];
    const float* value = (const float*)d_in[2];
    const int*   mask  = (const int*)d_in[3];     // proven int32 (R2 bit-identical)
    const float* Wa    = (const float*)d_in[4];
    const float* Ua    = (const float*)d_in[5];
    const float* scale = (const float*)d_in[6];
    float* out = (float*)d_out;

    float* qf2 = (float*)d_ws;                    // [4096,128] = 2 MB (premult)
    float* kT  = qf2 + Bb * Tq * Uu;              // [8][128][512] = 2 MB (compact)

    proj_kernel<<<(2 * Bb * Tq) / 16, 256, 0, stream>>>(query, key, Wa, Ua, mask, qf2, kT);
    attn_kernel<<<(Bb * Tq) / 8, 512, 0, stream>>>(qf2, kT, value, mask, scale, out);
}

// Round 12
// 170.973 us; speedup vs baseline: 1.0466x; 1.0466x over previous
//
#include <hip/hip_runtime.h>

// Problem constants (B=8, Tq=Tv=512, D=512, U=128)
constexpr int Bb = 8;
constexpr int Tq = 512;
constexpr int Tv = 512;
constexpr int Dd = 512;
constexpr int Uu = 128;
constexpr float C2LOG2E = 2.88539008177792681f;   // 2*log2(e)
constexpr float LOG2E   = 1.44269504088896341f;

// ---------------------------------------------------------------------------
// Kernel A: projections. 16 rows/block, 256 threads, 512 blocks.
// q half -> qf2[row][u] row-major. k half -> compact kT[b][u][pos[j]]; the
// 16 pos values come from an in-block 64-lane ballot scan of the mask.
// Both premultiplied by 2*log2e.
// ---------------------------------------------------------------------------
__global__ __launch_bounds__(256) void proj_kernel(
    const float* __restrict__ query,
    const float* __restrict__ key,
    const float* __restrict__ Wa,
    const float* __restrict__ Ua,
    const int* __restrict__ mask,
    float* __restrict__ qf2, float* __restrict__ kT)
{
    const int R    = blockIdx.x * 16;              // 0..8191
    const bool isQ = R < Bb * Tq;
    const float* __restrict__ src = isQ ? query : key;
    const float* __restrict__ W   = isQ ? Wa : Ua;
    const int Rloc = isQ ? R : R - Bb * Tq;        // 0..4095

    __shared__ float x[16 * Dd];                   // 32 KB
    __shared__ int posLoc[16];
    const int t = threadIdx.x;

    {   // stage 16 rows: 2048 float4, coalesced
        const float4* __restrict__ s4 =
            reinterpret_cast<const float4*>(src + (size_t)Rloc * Dd);
        float4* x4 = reinterpret_cast<float4*>(x);
#pragma unroll
        for (int m = 0; m < 8; ++m) x4[t + 256 * m] = s4[t + 256 * m];
    }
    if (!isQ && t < 64) {                          // wave-0 ballot scan -> pos
        const int b  = Rloc >> 9;
        const int j0 = Rloc & 511;                 // 16-aligned
        int base = 0;
#pragma unroll
        for (int c = 0; c < 8; ++c) {
            const int j = c * 64 + t;
            const int v = (mask[b * 512 + j] != 0);
            const unsigned long long bits = __ballot(v);
            const int pos = base + (int)__popcll(bits & ((1ull << t) - 1ull));
            if (j >= j0 && j < j0 + 16) posLoc[j - j0] = v ? pos : -1;
            base += (int)__popcll(bits);
        }
    }
    __syncthreads();

    const int ub = t & 63;
    const int rh = t >> 6;                         // 0..3
    float acc[4][2] = {{0,0},{0,0},{0,0},{0,0}};

#pragma unroll 2
    for (int d4 = 0; d4 < Dd / 4; ++d4) {
        const int d = d4 * 4;
        const float w0x = W[(d + 0) * Uu + ub],      w1x = W[(d + 0) * Uu + ub + 64];
        const float w0y = W[(d + 1) * Uu + ub],      w1y = W[(d + 1) * Uu + ub + 64];
        const float w0z = W[(d + 2) * Uu + ub],      w1z = W[(d + 2) * Uu + ub + 64];
        const float w0w = W[(d + 3) * Uu + ub],      w1w = W[(d + 3) * Uu + ub + 64];
#pragma unroll
        for (int k = 0; k < 4; ++k) {
            const float4 xv = *reinterpret_cast<const float4*>(x + (rh * 4 + k) * Dd + d);
            acc[k][0] = fmaf(xv.x, w0x, acc[k][0]);
            acc[k][0] = fmaf(xv.y, w0y, acc[k][0]);
            acc[k][0] = fmaf(xv.z, w0z, acc[k][0]);
            acc[k][0] = fmaf(xv.w, w0w, acc[k][0]);
            acc[k][1] = fmaf(xv.x, w1x, acc[k][1]);
            acc[k][1] = fmaf(xv.y, w1y, acc[k][1]);
            acc[k][1] = fmaf(xv.z, w1z, acc[k][1]);
            acc[k][1] = fmaf(xv.w, w1w, acc[k][1]);
        }
    }

    if (isQ) {
#pragma unroll
        for (int k = 0; k < 4; ++k) {
            const size_t row = (size_t)(Rloc + rh * 4 + k);
            qf2[row * Uu + ub]      = C2LOG2E * acc[k][0];
            qf2[row * Uu + ub + 64] = C2LOG2E * acc[k][1];
        }
    } else {
        float* __restrict__ kb = kT + (size_t)(Rloc >> 9) * Uu * Tv;
#pragma unroll
        for (int k = 0; k < 4; ++k) {
            const int p = posLoc[rh * 4 + k];
            if (p >= 0) {
                kb[(size_t)ub        * Tv + p] = C2LOG2E * acc[k][0];
                kb[(size_t)(ub + 64) * Tv + p] = C2LOG2E * acc[k][1];
            }
        }
    }
}

// ---------------------------------------------------------------------------
// Kernel B: attention over COMPACT keys. 8 query rows/block, 512 threads,
// 512 blocks. jl/cnt built in-block by ballot scan.
//   score : thread (s=t&255, rh=t>>8) -> key jc=s, rows rh*4..rh*4+3,
//           FULL u range, acc[4]; writes its own w rows directly (no combine).
//           Second block-uniform iteration if cnt>256.
//   softmax: wave wv -> row wv, over [0,cnt).
//   context: group g (0/1) owns a 4-aligned compact j-range; value rows via
//            jl indirection; partials combined via LDS pbuf.
// ---------------------------------------------------------------------------
__global__ __launch_bounds__(512) void attn_kernel(
    const float* __restrict__ qf2, const float* __restrict__ kT,
    const float* __restrict__ value,
    const int* __restrict__ mask,
    const float* __restrict__ scale,
    float* __restrict__ out)
{
    const int r0 = blockIdx.x * 8;            // first query row (0..4095)
    const int b  = r0 >> 9;
    const int t  = threadIdx.x;               // 0..511

    __shared__ float q2[8 * Uu];              // 4 KB
    __shared__ float s2[Uu];                  // 0.5 KB
    __shared__ int   jl[Tv];                  // 2 KB
    __shared__ float w[8 * Tv];               // 16 KB
    __shared__ float pbuf[8 * Dd];            // 16 KB (context partials)
    __shared__ float inv8[8];
    __shared__ int   cntS;

    jl[t] = 0;
    if (t < 256)
        reinterpret_cast<float4*>(q2)[t] =
            reinterpret_cast<const float4*>(qf2 + (size_t)r0 * Uu)[t];
    else if (t < 384) s2[t - 256] = scale[t - 256];
    __syncthreads();
    if (t < 64) {                             // wave-0 ballot scan -> jl, cnt
        int base = 0;
#pragma unroll
        for (int c = 0; c < 8; ++c) {
            const int j = c * 64 + t;
            const int v = (mask[b * 512 + j] != 0);
            const unsigned long long bits = __ballot(v);
            const int pos = base + (int)__popcll(bits & ((1ull << t) - 1ull));
            if (v) jl[pos] = j;
            base += (int)__popcll(bits);
        }
        if (t == 0) cntS = base;
    }
    __syncthreads();

    const int cnt   = cntS;
    const int cntp4 = (cnt + 3) & ~3;

    // ---- scores: row-split. thread (s, rh) -> key jc=s, rows rh*4..+3 ----
    const int s   = t & 255;
    const int rh  = t >> 8;                   // 0/1 (wave-uniform)
    const float* __restrict__ qh = q2 + rh * 4 * Uu;
    float* __restrict__ wh = w + rh * 4 * Tv;
    const int niter = (cntp4 + 255) >> 8;     // 1 or 2, block-uniform
    for (int it = 0; it < niter; ++it) {
        const int jc = s + it * 256;
        if (jc < cnt) {
            const float* __restrict__ kb = kT + (size_t)b * Uu * Tv + jc;
            float acc[4] = {0, 0, 0, 0};
#pragma unroll 2
            for (int u4 = 0; u4 < Uu / 4; ++u4) {
                const float kx = kb[(size_t)(u4 * 4 + 0) * Tv];
                const float ky = kb[(size_t)(u4 * 4 + 1) * Tv];
                const float kz = kb[(size_t)(u4 * 4 + 2) * Tv];
                const float kw = kb[(size_t)(u4 * 4 + 3) * Tv];
                const float4 sv = reinterpret_cast<const float4*>(s2)[u4];
#pragma unroll
                for (int i = 0; i < 4; ++i) {
                    const float4 qv = *reinterpret_cast<const float4*>(qh + i * Uu + u4 * 4);
                    float e0 = __builtin_amdgcn_exp2f(qv.x + kx);
                    float e1 = __builtin_amdgcn_exp2f(qv.y + ky);
                    float e2 = __builtin_amdgcn_exp2f(qv.z + kz);
                    float e3 = __builtin_amdgcn_exp2f(qv.w + kw);
                    acc[i] = fmaf(sv.x, __builtin_amdgcn_rcpf(e0 + 1.f), acc[i]);
                    acc[i] = fmaf(sv.y, __builtin_amdgcn_rcpf(e1 + 1.f), acc[i]);
                    acc[i] = fmaf(sv.z, __builtin_amdgcn_rcpf(e2 + 1.f), acc[i]);
                    acc[i] = fmaf(sv.w, __builtin_amdgcn_rcpf(e3 + 1.f), acc[i]);
                }
            }
#pragma unroll
            for (int i = 0; i < 4; ++i) wh[i * Tv + jc] = -2.f * acc[i];
        } else if (jc < cntp4) {
#pragma unroll
            for (int i = 0; i < 4; ++i) wh[i * Tv + jc] = 0.f;   // pad
        }
    }
    __syncthreads();

    // ---- softmax over [0,cnt): wave wv handles row wv ----
    {
        const int wv = t >> 6, ln = t & 63;
        float* __restrict__ row = w + wv * Tv;
        float vals[8];
        float m = -3e38f;
#pragma unroll
        for (int c = 0; c < 8; ++c) {
            const int e = ln + 64 * c;
            vals[c] = (e < cnt) ? row[e] : -3e38f;
            m = fmaxf(m, vals[c]);
        }
#pragma unroll
        for (int off = 32; off; off >>= 1) m = fmaxf(m, __shfl_xor(m, off, 64));
        float sum = 0.f;
#pragma unroll
        for (int c = 0; c < 8; ++c) {
            const int e = ln + 64 * c;
            if (e < cnt) {
                float ex = __builtin_amdgcn_exp2f((vals[c] - m) * LOG2E);
                row[e] = ex;
                sum += ex;
            }
        }
#pragma unroll
        for (int off = 32; off; off >>= 1) sum += __shfl_xor(sum, off, 64);
        if (ln == 0) inv8[wv] = 1.0f / sum;
    }
    __syncthreads();

    // ---- context over compact rows: group g owns a 4-aligned range ----
    const int mid  = ((cntp4 >> 1) + 3) & ~3;
    const int g  = t >> 8;                 // 0/1
    const int c  = t & 255;
    const int d0 = c * 2;
    const int jbeg = g ? mid : 0;
    const int jend = g ? cntp4 : mid;
    const float* __restrict__ vb = value + (size_t)b * Tv * Dd + d0;
    float ax[8], ay[8];
#pragma unroll
    for (int i = 0; i < 8; ++i) { ax[i] = 0.f; ay[i] = 0.f; }

    for (int jj = jbeg; jj < jend; jj += 4) {
        const int4 rows = *reinterpret_cast<const int4*>(jl + jj);
        const float2 v0 = *reinterpret_cast<const float2*>(vb + (size_t)rows.x * Dd);
        const float2 v1 = *reinterpret_cast<const float2*>(vb + (size_t)rows.y * Dd);
        const float2 v2 = *reinterpret_cast<const float2*>(vb + (size_t)rows.z * Dd);
        const float2 v3 = *reinterpret_cast<const float2*>(vb + (size_t)rows.w * Dd);
#pragma unroll
        for (int i = 0; i < 8; ++i) {
            const float4 wq = *reinterpret_cast<const float4*>(w + i * Tv + jj); // broadcast
            ax[i] = fmaf(wq.x, v0.x, ax[i]); ay[i] = fmaf(wq.x, v0.y, ay[i]);
            ax[i] = fmaf(wq.y, v1.x, ax[i]); ay[i] = fmaf(wq.y, v1.y, ay[i]);
            ax[i] = fmaf(wq.z, v2.x, ax[i]); ay[i] = fmaf(wq.z, v2.y, ay[i]);
            ax[i] = fmaf(wq.w, v3.x, ax[i]); ay[i] = fmaf(wq.w, v3.y, ay[i]);
        }
    }

    if (g == 1) {
#pragma unroll
        for (int i = 0; i < 8; ++i) {
            float2 p; p.x = ax[i]; p.y = ay[i];
            *reinterpret_cast<float2*>(pbuf + i * Dd + d0) = p;
        }
    }
    __syncthreads();
    if (g == 0) {
#pragma unroll
        for (int i = 0; i < 8; ++i) {
            const float inv = inv8[i];
            const float2 p1 = *reinterpret_cast<const float2*>(pbuf + i * Dd + d0);
            float2 o;
            o.x = (ax[i] + p1.x) * inv;
            o.y = (ay[i] + p1.y) * inv;
            *reinterpret_cast<float2*>(out + (size_t)(r0 + i) * Dd + d0) = o;
        }
    }
}

extern "C" void kernel_launch(void* const* d_in, const int* in_sizes, int n_in,
                              void* d_out, int out_size, void* d_ws, size_t ws_size,
                              hipStream_t stream)
{
    const float* query = (const float*)d_in[0];
    const float* key   = (const float*)d_in[1];
    const float* value = (const float*)d_in[2];
    const int*   mask  = (const int*)d_in[3];     // proven int32 (R2 bit-identical)
    const float* Wa    = (const float*)d_in[4];
    const float* Ua    = (const float*)d_in[5];
    const float* scale = (const float*)d_in[6];
    float* out = (float*)d_out;

    float* qf2 = (float*)d_ws;                    // [4096,128] = 2 MB (premult)
    float* kT  = qf2 + Bb * Tq * Uu;              // [8][128][512] = 2 MB (compact)

    proj_kernel<<<(2 * Bb * Tq) / 16, 256, 0, stream>>>(query, key, Wa, Ua, mask, qf2, kT);
    attn_kernel<<<(Bb * Tq) / 8, 512, 0, stream>>>(qf2, kT, value, mask, scale, out);
}

// Round 14
// 168.171 us; speedup vs baseline: 1.0640x; 1.0167x over previous
//
#include <hip/hip_runtime.h>

// Problem constants (B=8, Tq=Tv=512, D=512, U=128)
constexpr int Bb = 8;
constexpr int Tq = 512;
constexpr int Tv = 512;
constexpr int Dd = 512;
constexpr int Uu = 128;
constexpr float C2LOG2E = 2.88539008177792681f;   // 2*log2(e)
constexpr float LOG2E   = 1.44269504088896341f;

// ---------------------------------------------------------------------------
// Kernel A: projections. 16 rows/block, 256 threads, 512 blocks.
// q half -> qf2[row][u] row-major. k half -> compact kT[b][u][pos[j]]; the
// 16 pos values come from an in-block 64-lane ballot scan of the mask.
// Both premultiplied by 2*log2e.
// ---------------------------------------------------------------------------
__global__ __launch_bounds__(256) void proj_kernel(
    const float* __restrict__ query,
    const float* __restrict__ key,
    const float* __restrict__ Wa,
    const float* __restrict__ Ua,
    const int* __restrict__ mask,
    float* __restrict__ qf2, float* __restrict__ kT)
{
    const int R    = blockIdx.x * 16;              // 0..8191
    const bool isQ = R < Bb * Tq;
    const float* __restrict__ src = isQ ? query : key;
    const float* __restrict__ W   = isQ ? Wa : Ua;
    const int Rloc = isQ ? R : R - Bb * Tq;        // 0..4095

    __shared__ float x[16 * Dd];                   // 32 KB
    __shared__ int posLoc[16];
    const int t = threadIdx.x;

    {   // stage 16 rows: 2048 float4, coalesced
        const float4* __restrict__ s4 =
            reinterpret_cast<const float4*>(src + (size_t)Rloc * Dd);
        float4* x4 = reinterpret_cast<float4*>(x);
#pragma unroll
        for (int m = 0; m < 8; ++m) x4[t + 256 * m] = s4[t + 256 * m];
    }
    if (!isQ && t < 64) {                          // wave-0 ballot scan -> pos
        const int b  = Rloc >> 9;
        const int j0 = Rloc & 511;                 // 16-aligned
        int base = 0;
#pragma unroll
        for (int c = 0; c < 8; ++c) {
            const int j = c * 64 + t;
            const int v = (mask[b * 512 + j] != 0);
            const unsigned long long bits = __ballot(v);
            const int pos = base + (int)__popcll(bits & ((1ull << t) - 1ull));
            if (j >= j0 && j < j0 + 16) posLoc[j - j0] = v ? pos : -1;
            base += (int)__popcll(bits);
        }
    }
    __syncthreads();

    const int ub = t & 63;
    const int rh = t >> 6;                         // 0..3
    float acc[4][2] = {{0,0},{0,0},{0,0},{0,0}};

#pragma unroll 2
    for (int d4 = 0; d4 < Dd / 4; ++d4) {
        const int d = d4 * 4;
        const float w0x = W[(d + 0) * Uu + ub],      w1x = W[(d + 0) * Uu + ub + 64];
        const float w0y = W[(d + 1) * Uu + ub],      w1y = W[(d + 1) * Uu + ub + 64];
        const float w0z = W[(d + 2) * Uu + ub],      w1z = W[(d + 2) * Uu + ub + 64];
        const float w0w = W[(d + 3) * Uu + ub],      w1w = W[(d + 3) * Uu + ub + 64];
#pragma unroll
        for (int k = 0; k < 4; ++k) {
            const float4 xv = *reinterpret_cast<const float4*>(x + (rh * 4 + k) * Dd + d);
            acc[k][0] = fmaf(xv.x, w0x, acc[k][0]);
            acc[k][0] = fmaf(xv.y, w0y, acc[k][0]);
            acc[k][0] = fmaf(xv.z, w0z, acc[k][0]);
            acc[k][0] = fmaf(xv.w, w0w, acc[k][0]);
            acc[k][1] = fmaf(xv.x, w1x, acc[k][1]);
            acc[k][1] = fmaf(xv.y, w1y, acc[k][1]);
            acc[k][1] = fmaf(xv.z, w1z, acc[k][1]);
            acc[k][1] = fmaf(xv.w, w1w, acc[k][1]);
        }
    }

    if (isQ) {
#pragma unroll
        for (int k = 0; k < 4; ++k) {
            const size_t row = (size_t)(Rloc + rh * 4 + k);
            qf2[row * Uu + ub]      = C2LOG2E * acc[k][0];
            qf2[row * Uu + ub + 64] = C2LOG2E * acc[k][1];
        }
    } else {
        float* __restrict__ kb = kT + (size_t)(Rloc >> 9) * Uu * Tv;
#pragma unroll
        for (int k = 0; k < 4; ++k) {
            const int p = posLoc[rh * 4 + k];
            if (p >= 0) {
                kb[(size_t)ub        * Tv + p] = C2LOG2E * acc[k][0];
                kb[(size_t)(ub + 64) * Tv + p] = C2LOG2E * acc[k][1];
            }
        }
    }
}

// ---------------------------------------------------------------------------
// Kernel B: attention over COMPACT keys. 4 query rows/block, 256 threads,
// 1024 blocks (4 blocks/CU, all 4 waves active in every phase).
//   score : thread jc=t (<cnt; ~full coverage at cnt~256), acc[4], full u.
//           Block-uniform extra pass if cnt>256.
//   softmax: wave wv -> row wv, over [0,cnt).
//   context: thread t -> d pair d0=2t, all 4 rows, full compact j-range
//            (no partial combine needed). Value rows via jl indirection.
// ---------------------------------------------------------------------------
__global__ __launch_bounds__(256, 4) void attn_kernel(
    const float* __restrict__ qf2, const float* __restrict__ kT,
    const float* __restrict__ value,
    const int* __restrict__ mask,
    const float* __restrict__ scale,
    float* __restrict__ out)
{
    const int r0 = blockIdx.x * 4;            // first query row (0..4095)
    const int b  = r0 >> 9;
    const int t  = threadIdx.x;               // 0..255

    __shared__ float q2[4 * Uu];              // 2 KB
    __shared__ float s2[Uu];                  // 0.5 KB
    __shared__ int   jl[Tv];                  // 2 KB
    __shared__ float w[4 * Tv];               // 8 KB
    __shared__ float inv4[4];
    __shared__ int   cntS;

    jl[t] = 0; jl[t + 256] = 0;
    if (t < 128)
        reinterpret_cast<float4*>(q2)[t] =
            reinterpret_cast<const float4*>(qf2 + (size_t)r0 * Uu)[t];
    else s2[t - 128] = scale[t - 128];
    __syncthreads();
    if (t < 64) {                             // wave-0 ballot scan -> jl, cnt
        int base = 0;
#pragma unroll
        for (int c = 0; c < 8; ++c) {
            const int j = c * 64 + t;
            const int v = (mask[b * 512 + j] != 0);
            const unsigned long long bits = __ballot(v);
            const int pos = base + (int)__popcll(bits & ((1ull << t) - 1ull));
            if (v) jl[pos] = j;
            base += (int)__popcll(bits);
        }
        if (t == 0) cntS = base;
    }
    __syncthreads();

    const int cnt   = cntS;
    const int cntp4 = (cnt + 3) & ~3;

    // ---- scores: thread jc=t (+256 in uniform second pass if needed) ----
    const int niter = (cntp4 + 255) >> 8;     // 1 or 2, block-uniform
    for (int it = 0; it < niter; ++it) {
        const int jc = t + it * 256;
        if (jc < cnt) {
            const float* __restrict__ kb = kT + (size_t)b * Uu * Tv + jc;
            float acc[4] = {0, 0, 0, 0};
#pragma unroll 2
            for (int u4 = 0; u4 < Uu / 4; ++u4) {
                const float kx = kb[(size_t)(u4 * 4 + 0) * Tv];
                const float ky = kb[(size_t)(u4 * 4 + 1) * Tv];
                const float kz = kb[(size_t)(u4 * 4 + 2) * Tv];
                const float kw = kb[(size_t)(u4 * 4 + 3) * Tv];
                const float4 sv = reinterpret_cast<const float4*>(s2)[u4];
#pragma unroll
                for (int i = 0; i < 4; ++i) {
                    const float4 qv = *reinterpret_cast<const float4*>(q2 + i * Uu + u4 * 4);
                    float e0 = __builtin_amdgcn_exp2f(qv.x + kx);
                    float e1 = __builtin_amdgcn_exp2f(qv.y + ky);
                    float e2 = __builtin_amdgcn_exp2f(qv.z + kz);
                    float e3 = __builtin_amdgcn_exp2f(qv.w + kw);
                    acc[i] = fmaf(sv.x, __builtin_amdgcn_rcpf(e0 + 1.f), acc[i]);
                    acc[i] = fmaf(sv.y, __builtin_amdgcn_rcpf(e1 + 1.f), acc[i]);
                    acc[i] = fmaf(sv.z, __builtin_amdgcn_rcpf(e2 + 1.f), acc[i]);
                    acc[i] = fmaf(sv.w, __builtin_amdgcn_rcpf(e3 + 1.f), acc[i]);
                }
            }
#pragma unroll
            for (int i = 0; i < 4; ++i) w[i * Tv + jc] = -2.f * acc[i];
        } else if (jc < cntp4) {
#pragma unroll
            for (int i = 0; i < 4; ++i) w[i * Tv + jc] = 0.f;   // pad
        }
    }
    __syncthreads();

    // ---- softmax over [0,cnt): wave wv handles row wv (4 waves, 4 rows) ----
    {
        const int wv = t >> 6, ln = t & 63;
        float* __restrict__ row = w + wv * Tv;
        float vals[8];
        float m = -3e38f;
#pragma unroll
        for (int c = 0; c < 8; ++c) {
            const int e = ln + 64 * c;
            vals[c] = (e < cnt) ? row[e] : -3e38f;
            m = fmaxf(m, vals[c]);
        }
#pragma unroll
        for (int off = 32; off; off >>= 1) m = fmaxf(m, __shfl_xor(m, off, 64));
        float sum = 0.f;
#pragma unroll
        for (int c = 0; c < 8; ++c) {
            const int e = ln + 64 * c;
            if (e < cnt) {
                float ex = __builtin_amdgcn_exp2f((vals[c] - m) * LOG2E);
                row[e] = ex;
                sum += ex;
            }
        }
#pragma unroll
        for (int off = 32; off; off >>= 1) sum += __shfl_xor(sum, off, 64);
        if (ln == 0) inv4[wv] = 1.0f / sum;
    }
    __syncthreads();

    // ---- context: thread t -> d pair, all 4 rows, full compact range ----
    const int d0 = t * 2;
    const float* __restrict__ vb = value + (size_t)b * Tv * Dd + d0;
    float ax[4], ay[4];
#pragma unroll
    for (int i = 0; i < 4; ++i) { ax[i] = 0.f; ay[i] = 0.f; }

    for (int jj = 0; jj < cntp4; jj += 4) {
        const int4 rows = *reinterpret_cast<const int4*>(jl + jj);
        const float2 v0 = *reinterpret_cast<const float2*>(vb + (size_t)rows.x * Dd);
        const float2 v1 = *reinterpret_cast<const float2*>(vb + (size_t)rows.y * Dd);
        const float2 v2 = *reinterpret_cast<const float2*>(vb + (size_t)rows.z * Dd);
        const float2 v3 = *reinterpret_cast<const float2*>(vb + (size_t)rows.w * Dd);
#pragma unroll
        for (int i = 0; i < 4; ++i) {
            const float4 wq = *reinterpret_cast<const float4*>(w + i * Tv + jj); // broadcast
            ax[i] = fmaf(wq.x, v0.x, ax[i]); ay[i] = fmaf(wq.x, v0.y, ay[i]);
            ax[i] = fmaf(wq.y, v1.x, ax[i]); ay[i] = fmaf(wq.y, v1.y, ay[i]);
            ax[i] = fmaf(wq.z, v2.x, ax[i]); ay[i] = fmaf(wq.z, v2.y, ay[i]);
            ax[i] = fmaf(wq.w, v3.x, ax[i]); ay[i] = fmaf(wq.w, v3.y, ay[i]);
        }
    }

#pragma unroll
    for (int i = 0; i < 4; ++i) {
        const float inv = inv4[i];
        float2 o;
        o.x = ax[i] * inv;
        o.y = ay[i] * inv;
        *reinterpret_cast<float2*>(out + (size_t)(r0 + i) * Dd + d0) = o;
    }
}

extern "C" void kernel_launch(void* const* d_in, const int* in_sizes, int n_in,
                              void* d_out, int out_size, void* d_ws, size_t ws_size,
                              hipStream_t stream)
{
    const float* query = (const float*)d_in[0];
    const float* key   = (const float*)d_in[1];
    const float* value = (const float*)d_in[2];
    const int*   mask  = (const int*)d_in[3];     // proven int32 (R2 bit-identical)
    const float* Wa    = (const float*)d_in[4];
    const float* Ua    = (const float*)d_in[5];
    const float* scale = (const float*)d_in[6];
    float* out = (float*)d_out;

    float* qf2 = (float*)d_ws;                    // [4096,128] = 2 MB (premult)
    float* kT  = qf2 + Bb * Tq * Uu;              // [8][128][512] = 2 MB (compact)

    proj_kernel<<<(2 * Bb * Tq) / 16, 256, 0, stream>>>(query, key, Wa, Ua, mask, qf2, kT);
    attn_kernel<<<(Bb * Tq) / 4, 256, 0, stream>>>(qf2, kT, value, mask, scale, out);
}

// Round 15
// 165.028 us; speedup vs baseline: 1.0843x; 1.0190x over previous
//
#include <hip/hip_runtime.h>

// Problem constants (B=8, Tq=Tv=512, D=512, U=128)
constexpr int Bb = 8;
constexpr int Tq = 512;
constexpr int Tv = 512;
constexpr int Dd = 512;
constexpr int Uu = 128;
constexpr float C2LOG2E = 2.88539008177792681f;   // 2*log2(e)
constexpr float LOG2E   = 1.44269504088896341f;

// ---------------------------------------------------------------------------
// Kernel A: projections. 16 rows/block, 256 threads, 512 blocks.
// q half -> qf2[row][u] row-major. k half -> compact, u4-INTERLEAVED
//   kT[b][u4][pos][comp] (float4 per (u4,pos)) so the score loop loads one
//   dwordx4 instead of 4 strided dwords. pos via in-block ballot scan.
// Both premultiplied by 2*log2e.
// ---------------------------------------------------------------------------
__global__ __launch_bounds__(256) void proj_kernel(
    const float* __restrict__ query,
    const float* __restrict__ key,
    const float* __restrict__ Wa,
    const float* __restrict__ Ua,
    const int* __restrict__ mask,
    float* __restrict__ qf2, float* __restrict__ kT)
{
    const int R    = blockIdx.x * 16;              // 0..8191
    const bool isQ = R < Bb * Tq;
    const float* __restrict__ src = isQ ? query : key;
    const float* __restrict__ W   = isQ ? Wa : Ua;
    const int Rloc = isQ ? R : R - Bb * Tq;        // 0..4095

    __shared__ float x[16 * Dd];                   // 32 KB
    __shared__ int posLoc[16];
    const int t = threadIdx.x;

    {   // stage 16 rows: 2048 float4, coalesced
        const float4* __restrict__ s4 =
            reinterpret_cast<const float4*>(src + (size_t)Rloc * Dd);
        float4* x4 = reinterpret_cast<float4*>(x);
#pragma unroll
        for (int m = 0; m < 8; ++m) x4[t + 256 * m] = s4[t + 256 * m];
    }
    if (!isQ && t < 64) {                          // wave-0 ballot scan -> pos
        const int b  = Rloc >> 9;
        const int j0 = Rloc & 511;                 // 16-aligned
        int base = 0;
#pragma unroll
        for (int c = 0; c < 8; ++c) {
            const int j = c * 64 + t;
            const int v = (mask[b * 512 + j] != 0);
            const unsigned long long bits = __ballot(v);
            const int pos = base + (int)__popcll(bits & ((1ull << t) - 1ull));
            if (j >= j0 && j < j0 + 16) posLoc[j - j0] = v ? pos : -1;
            base += (int)__popcll(bits);
        }
    }
    __syncthreads();

    const int ub = t & 63;
    const int rh = t >> 6;                         // 0..3
    float acc[4][2] = {{0,0},{0,0},{0,0},{0,0}};

#pragma unroll 2
    for (int d4 = 0; d4 < Dd / 4; ++d4) {
        const int d = d4 * 4;
        const float w0x = W[(d + 0) * Uu + ub],      w1x = W[(d + 0) * Uu + ub + 64];
        const float w0y = W[(d + 1) * Uu + ub],      w1y = W[(d + 1) * Uu + ub + 64];
        const float w0z = W[(d + 2) * Uu + ub],      w1z = W[(d + 2) * Uu + ub + 64];
        const float w0w = W[(d + 3) * Uu + ub],      w1w = W[(d + 3) * Uu + ub + 64];
#pragma unroll
        for (int k = 0; k < 4; ++k) {
            const float4 xv = *reinterpret_cast<const float4*>(x + (rh * 4 + k) * Dd + d);
            acc[k][0] = fmaf(xv.x, w0x, acc[k][0]);
            acc[k][0] = fmaf(xv.y, w0y, acc[k][0]);
            acc[k][0] = fmaf(xv.z, w0z, acc[k][0]);
            acc[k][0] = fmaf(xv.w, w0w, acc[k][0]);
            acc[k][1] = fmaf(xv.x, w1x, acc[k][1]);
            acc[k][1] = fmaf(xv.y, w1y, acc[k][1]);
            acc[k][1] = fmaf(xv.z, w1z, acc[k][1]);
            acc[k][1] = fmaf(xv.w, w1w, acc[k][1]);
        }
    }

    if (isQ) {
#pragma unroll
        for (int k = 0; k < 4; ++k) {
            const size_t row = (size_t)(Rloc + rh * 4 + k);
            qf2[row * Uu + ub]      = C2LOG2E * acc[k][0];
            qf2[row * Uu + ub + 64] = C2LOG2E * acc[k][1];
        }
    } else {
        // interleaved store: kT[b][(u>>2)*512 + p][u&3]
        float* __restrict__ kb = kT + (size_t)(Rloc >> 9) * Uu * Tv;
        const int u4a = ub >> 2, ca = ub & 3;
#pragma unroll
        for (int k = 0; k < 4; ++k) {
            const int p = posLoc[rh * 4 + k];
            if (p >= 0) {
                kb[(size_t)(u4a        * Tv + p) * 4 + ca] = C2LOG2E * acc[k][0];
                kb[(size_t)((u4a + 16) * Tv + p) * 4 + ca] = C2LOG2E * acc[k][1];
            }
        }
    }
}

// ---------------------------------------------------------------------------
// Kernel B: attention over COMPACT keys (R10 structure — best measured),
// with float4 kT loads. 8 query rows/block, 512 threads, 512 blocks.
//   score : thread jc=t (<cnt) single pass, acc[8]; one dwordx4 k-load per u4.
//   softmax: wave wv -> row wv, over [0,cnt).
//   context: group g (0/1) owns a 4-aligned compact j-range; value rows via
//            jl indirection; partials combined via LDS pbuf.
// ---------------------------------------------------------------------------
__global__ __launch_bounds__(512) void attn_kernel(
    const float* __restrict__ qf2, const float* __restrict__ kT,
    const float* __restrict__ value,
    const int* __restrict__ mask,
    const float* __restrict__ scale,
    float* __restrict__ out)
{
    const int r0 = blockIdx.x * 8;            // first query row (0..4095)
    const int b  = r0 >> 9;
    const int t  = threadIdx.x;               // 0..511

    __shared__ float q2[8 * Uu];              // 4 KB
    __shared__ float s2[Uu];                  // 0.5 KB
    __shared__ int   jl[Tv];                  // 2 KB
    __shared__ float w[8 * Tv];               // 16 KB
    __shared__ float pbuf[8 * Dd];            // 16 KB (context partials)
    __shared__ float inv8[8];
    __shared__ int   cntS;

    jl[t] = 0;
    if (t < 256)
        reinterpret_cast<float4*>(q2)[t] =
            reinterpret_cast<const float4*>(qf2 + (size_t)r0 * Uu)[t];
    else if (t < 384) s2[t - 256] = scale[t - 256];
    __syncthreads();
    if (t < 64) {                             // wave-0 ballot scan -> jl, cnt
        int base = 0;
#pragma unroll
        for (int c = 0; c < 8; ++c) {
            const int j = c * 64 + t;
            const int v = (mask[b * 512 + j] != 0);
            const unsigned long long bits = __ballot(v);
            const int pos = base + (int)__popcll(bits & ((1ull << t) - 1ull));
            if (v) jl[pos] = j;
            base += (int)__popcll(bits);
        }
        if (t == 0) cntS = base;
    }
    __syncthreads();

    const int cnt   = cntS;
    const int cntp4 = (cnt + 3) & ~3;

    // ---- scores over compact keys: thread jc=t, acc[8], float4 k-loads ----
    const int jc = t;
    if (jc < cnt) {
        const float4* __restrict__ kb4 =
            reinterpret_cast<const float4*>(kT) + (size_t)b * 32 * Tv + jc;
        float acc[8] = {0,0,0,0,0,0,0,0};
#pragma unroll 2
        for (int u4 = 0; u4 < Uu / 4; ++u4) {
            const float4 kv = kb4[(size_t)u4 * Tv];
            const float4 sv = reinterpret_cast<const float4*>(s2)[u4];
#pragma unroll
            for (int i = 0; i < 8; ++i) {
                const float4 qv = *reinterpret_cast<const float4*>(q2 + i * Uu + u4 * 4);
                float e0 = __builtin_amdgcn_exp2f(qv.x + kv.x);
                float e1 = __builtin_amdgcn_exp2f(qv.y + kv.y);
                float e2 = __builtin_amdgcn_exp2f(qv.z + kv.z);
                float e3 = __builtin_amdgcn_exp2f(qv.w + kv.w);
                acc[i] = fmaf(sv.x, __builtin_amdgcn_rcpf(e0 + 1.f), acc[i]);
                acc[i] = fmaf(sv.y, __builtin_amdgcn_rcpf(e1 + 1.f), acc[i]);
                acc[i] = fmaf(sv.z, __builtin_amdgcn_rcpf(e2 + 1.f), acc[i]);
                acc[i] = fmaf(sv.w, __builtin_amdgcn_rcpf(e3 + 1.f), acc[i]);
            }
        }
#pragma unroll
        for (int i = 0; i < 8; ++i) w[i * Tv + jc] = -2.f * acc[i];
    } else {
#pragma unroll
        for (int i = 0; i < 8; ++i) w[i * Tv + jc] = 0.f;   // pad
    }
    __syncthreads();

    // ---- softmax over [0,cnt): wave wv handles row wv ----
    {
        const int wv = t >> 6, ln = t & 63;
        float* __restrict__ row = w + wv * Tv;
        float vals[8];
        float m = -3e38f;
#pragma unroll
        for (int c = 0; c < 8; ++c) {
            const int e = ln + 64 * c;
            vals[c] = (e < cnt) ? row[e] : -3e38f;
            m = fmaxf(m, vals[c]);
        }
#pragma unroll
        for (int off = 32; off; off >>= 1) m = fmaxf(m, __shfl_xor(m, off, 64));
        float sum = 0.f;
#pragma unroll
        for (int c = 0; c < 8; ++c) {
            const int e = ln + 64 * c;
            if (e < cnt) {
                float ex = __builtin_amdgcn_exp2f((vals[c] - m) * LOG2E);
                row[e] = ex;
                sum += ex;
            }
        }
#pragma unroll
        for (int off = 32; off; off >>= 1) sum += __shfl_xor(sum, off, 64);
        if (ln == 0) inv8[wv] = 1.0f / sum;
    }
    __syncthreads();

    // ---- context over compact rows: group g owns a 4-aligned range ----
    const int mid = ((cntp4 >> 1) + 3) & ~3;
    const int g  = t >> 8;                 // 0/1
    const int c  = t & 255;
    const int d0 = c * 2;
    const int jbeg = g ? mid : 0;
    const int jend = g ? cntp4 : mid;
    const float* __restrict__ vb = value + (size_t)b * Tv * Dd + d0;
    float ax[8], ay[8];
#pragma unroll
    for (int i = 0; i < 8; ++i) { ax[i] = 0.f; ay[i] = 0.f; }

    for (int jj = jbeg; jj < jend; jj += 4) {
        const int4 rows = *reinterpret_cast<const int4*>(jl + jj);
        const float2 v0 = *reinterpret_cast<const float2*>(vb + (size_t)rows.x * Dd);
        const float2 v1 = *reinterpret_cast<const float2*>(vb + (size_t)rows.y * Dd);
        const float2 v2 = *reinterpret_cast<const float2*>(vb + (size_t)rows.z * Dd);
        const float2 v3 = *reinterpret_cast<const float2*>(vb + (size_t)rows.w * Dd);
#pragma unroll
        for (int i = 0; i < 8; ++i) {
            const float4 wq = *reinterpret_cast<const float4*>(w + i * Tv + jj); // broadcast
            ax[i] = fmaf(wq.x, v0.x, ax[i]); ay[i] = fmaf(wq.x, v0.y, ay[i]);
            ax[i] = fmaf(wq.y, v1.x, ax[i]); ay[i] = fmaf(wq.y, v1.y, ay[i]);
            ax[i] = fmaf(wq.z, v2.x, ax[i]); ay[i] = fmaf(wq.z, v2.y, ay[i]);
            ax[i] = fmaf(wq.w, v3.x, ax[i]); ay[i] = fmaf(wq.w, v3.y, ay[i]);
        }
    }

    if (g == 1) {
#pragma unroll
        for (int i = 0; i < 8; ++i) {
            float2 p; p.x = ax[i]; p.y = ay[i];
            *reinterpret_cast<float2*>(pbuf + i * Dd + d0) = p;
        }
    }
    __syncthreads();
    if (g == 0) {
#pragma unroll
        for (int i = 0; i < 8; ++i) {
            const float inv = inv8[i];
            const float2 p1 = *reinterpret_cast<const float2*>(pbuf + i * Dd + d0);
            float2 o;
            o.x = (ax[i] + p1.x) * inv;
            o.y = (ay[i] + p1.y) * inv;
            *reinterpret_cast<float2*>(out + (size_t)(r0 + i) * Dd + d0) = o;
        }
    }
}

extern "C" void kernel_launch(void* const* d_in, const int* in_sizes, int n_in,
                              void* d_out, int out_size, void* d_ws, size_t ws_size,
                              hipStream_t stream)
{
    const float* query = (const float*)d_in[0];
    const float* key   = (const float*)d_in[1];
    const float* value = (const float*)d_in[2];
    const int*   mask  = (const int*)d_in[3];     // proven int32 (R2 bit-identical)
    const float* Wa    = (const float*)d_in[4];
    const float* Ua    = (const float*)d_in[5];
    const float* scale = (const float*)d_in[6];
    float* out = (float*)d_out;

    float* qf2 = (float*)d_ws;                    // [4096,128] = 2 MB (premult)
    float* kT  = qf2 + Bb * Tq * Uu;              // [8][32][512] float4 = 2 MB (compact, u4-interleaved)

    proj_kernel<<<(2 * Bb * Tq) / 16, 256, 0, stream>>>(query, key, Wa, Ua, mask, qf2, kT);
    attn_kernel<<<(Bb * Tq) / 8, 512, 0, stream>>>(qf2, kT, value, mask, scale, out);
}